// Round 15
// baseline (59.843 us; speedup 1.0000x reference)
//
#include <hip/hip_runtime.h>

namespace {

constexpr int   kT = 512, kC = 512, kL = 128, kBlank = 511;
constexpr int   kCH  = 16;         // rows per chunk
constexpr int   kNCH = kT / kCH;   // 32 chunks
constexpr float kEps = 1e-7f, kLn2 = 0.6931471805599453f;

typedef float __attribute__((address_space(1))) f32g;
typedef float __attribute__((address_space(3))) f32l;

// Coalesced width-16 global->LDS: 64 lanes x 16B = 1KB (half a row).
__device__ __forceinline__ void glds16(const float* g, float* l) {
    __builtin_amdgcn_global_load_lds((const f32g*)g, (f32l*)l, 16, 0, 0);
}
__device__ __forceinline__ float rlane(float x, int l) {
    return __int_as_float(__builtin_amdgcn_readlane(__float_as_int(x), l));
}
__device__ __forceinline__ float bperm(int a, float x) {
    return __int_as_float(__builtin_amdgcn_ds_bpermute(a, __float_as_int(x)));
}
__device__ __forceinline__ float LOG2(float x) { return __builtin_amdgcn_logf(x); }

// 16 column-gather LDS reads from one base VGPR + row-stride immediates.
// Opaque to the compiler's waitcnt pass -> no conservative vmcnt(0) drain
// against the in-flight global_load_lds stream (the r2 disease).
#define GATHER16(dst_, addr_)                                                 \
    asm volatile("ds_read_b32 %0, %16 offset:0\n\t"                           \
                 "ds_read_b32 %1, %16 offset:2048\n\t"                        \
                 "ds_read_b32 %2, %16 offset:4096\n\t"                        \
                 "ds_read_b32 %3, %16 offset:6144\n\t"                        \
                 "ds_read_b32 %4, %16 offset:8192\n\t"                        \
                 "ds_read_b32 %5, %16 offset:10240\n\t"                       \
                 "ds_read_b32 %6, %16 offset:12288\n\t"                       \
                 "ds_read_b32 %7, %16 offset:14336\n\t"                       \
                 "ds_read_b32 %8, %16 offset:16384\n\t"                       \
                 "ds_read_b32 %9, %16 offset:18432\n\t"                       \
                 "ds_read_b32 %10, %16 offset:20480\n\t"                      \
                 "ds_read_b32 %11, %16 offset:22528\n\t"                      \
                 "ds_read_b32 %12, %16 offset:24576\n\t"                      \
                 "ds_read_b32 %13, %16 offset:26624\n\t"                      \
                 "ds_read_b32 %14, %16 offset:28672\n\t"                      \
                 "ds_read_b32 %15, %16 offset:30720"                          \
                 : "=&v"(dst_[0]), "=&v"(dst_[1]), "=&v"(dst_[2]),            \
                   "=&v"(dst_[3]), "=&v"(dst_[4]), "=&v"(dst_[5]),            \
                   "=&v"(dst_[6]), "=&v"(dst_[7]), "=&v"(dst_[8]),            \
                   "=&v"(dst_[9]), "=&v"(dst_[10]), "=&v"(dst_[11]),          \
                   "=&v"(dst_[12]), "=&v"(dst_[13]), "=&v"(dst_[14]),         \
                   "=&v"(dst_[15])                                            \
                 : "v"(addr_))

__global__ __launch_bounds__(64, 1) void ctc_fwd_kernel(
        const int* __restrict__ labels,
        const float* __restrict__ y_pred,
        float* __restrict__ out) {
    __shared__ __align__(16) float buf[2][kCH][kC];   // 64 KiB, wave-private

    const int lane = (int)threadIdx.x;   // single wave per block
    const int b    = (int)blockIdx.x;
    const float* yp  = y_pred + (size_t)b * kT * kC;
    const int*   lab = labels + b * kL;

    // ---- state s = 4*lane + k (k=0..3), + scalar state 256 (r11-proven) ----
    const int l0  = lab[2 * lane];
    const int l1v = lab[2 * lane + 1];
    const int lm  = (lane >= 1) ? lab[2 * lane - 1] : 0;
    const int cls1 = l0, cls3 = l1v;
    const float skp1 = (lane >= 1 && l0 != lm) ? 1.f : 0.f;
    const float skp3 = (l1v != l0) ? 1.f : 0.f;
    const int addr1 = (lane - 1) << 2;   // bpermute: lane i <- lane i-1

    // per-lane LDS gather bases (buffer 0); buffer 1 = +32768 bytes
    const unsigned aBb = (unsigned)(uintptr_t)&buf[0][0][kBlank];
    const unsigned aB1 = (unsigned)(uintptr_t)&buf[0][0][cls1];
    const unsigned aB3 = (unsigned)(uintptr_t)&buf[0][0][cls3];

    // drain label loads: from here on the VMEM stream is PURE glds16,
    // so our vmcnt counting is exact by construction.
    asm volatile("s_waitcnt vmcnt(0)" ::: "memory");
    __builtin_amdgcn_sched_barrier(0);

    // ---- prologue: stage chunks 0,1 (chunk c -> slot c&1) ----
    for (int ch = 0; ch < 2; ++ch)
        for (int r = 0; r < kCH; ++r) {
            const float* row = yp + (size_t)(ch * kCH + r) * kC;
            glds16(row + lane * 4,       &buf[ch][r][0]);
            glds16(row + 256 + lane * 4, &buf[ch][r][256]);
        }
    asm volatile("s_waitcnt vmcnt(32)" ::: "memory");   // chunk 0 resident

    float g_rb[kCH], g_r1[kCH], g_r3[kCH];
    GATHER16(g_rb, aBb);
    GATHER16(g_r1, aB1);
    GATHER16(g_r3, aB3);
    asm volatile("s_waitcnt lgkmcnt(0)" ::: "memory");
    __builtin_amdgcn_sched_barrier(0);

    // ---- linear-domain scaled forward; t=0 via lane0-only injection ----
    float a0 = 0.f, a1 = 0.f, a2 = 0.f, a3 = 0.f, a256 = 0.f, etot = 0.f;
    float inj = (lane == 0) ? 1.f : 0.f;

    for (int c = 0; c < kNCH; ++c) {
        // issue chunk c+2 into slot c&1 (freed: chunk c now lives in regs);
        // delivery overlaps the steps below.
        if (c + 2 < kNCH) {
            float (*bS)[kC] = buf[c & 1];
            for (int r = 0; r < kCH; ++r) {
                const float* row = yp + (size_t)((c + 2) * kCH + r) * kC;
                glds16(row + lane * 4,       &bS[r][0]);
                glds16(row + 256 + lane * 4, &bS[r][256]);
            }
        }
        // ---- 16 register-only recurrence steps (r13 body, bit-exact) ----
#pragma unroll
        for (int r = 0; r < kCH; ++r) {
            const float pb = g_rb[r] + kEps;   // blank prob (k=0,2,256)
            const float p1 = g_r1[r] + kEps;
            const float p3 = g_r3[r] + kEps;
            float sh3 = bperm(addr1, a3);      // prev-lane a3 (state 4l-1)
            sh3 = (lane == 0) ? 0.f : sh3;
            const float a255 = rlane(a3, 63);  // state 255 (pre-update)
            const float b0 = (a0 + sh3 + inj) * pb;              // s=4l
            const float b1 = (a1 + a0 + skp1 * sh3 + inj) * p1;  // s=4l+1
            const float b2 = (a2 + a1) * pb;                     // s=4l+2
            const float b3 = (a3 + a2 + skp3 * a1) * p3;         // s=4l+3
            a256 = (a256 + a255) * pb;                           // s=256
            a0 = b0; a1 = b1; a2 = b2; a3 = b3;
            inj = 0.f;
        }
        // lossless power-of-2 renorm every 2 chunks (32 steps)
        if (c & 1) {
            float m = fmaxf(fmaxf(a0, a1), fmaxf(a2, a3));
#pragma unroll
            for (int i = 1; i < 64; i <<= 1) m = fmaxf(m, __shfl_xor(m, i));
            m = fmaxf(m, a256);
            const int ex = (__float_as_int(m) >> 23) & 0xFF;
            if (ex > 1) {
                const float sc = __int_as_float((254 - ex) << 23); // 2^(127-ex)
                a0 *= sc; a1 *= sc; a2 *= sc; a3 *= sc; a256 *= sc;
                etot += (float)(ex - 127);
            }
        }
        // ---- wait chunk c+1 resident (counted; 0 only at the tail), then
        //      gather it into registers for the next iteration ----
        if (c + 1 < kNCH) {
            if (c + 2 < kNCH)
                asm volatile("s_waitcnt vmcnt(32)" ::: "memory");
            else
                asm volatile("s_waitcnt vmcnt(0)" ::: "memory");
            const unsigned off = (unsigned)(((c + 1) & 1) * (kCH * kC * 4));
            GATHER16(g_rb, aBb + off);
            GATHER16(g_r1, aB1 + off);
            GATHER16(g_r3, aB3 + off);
            asm volatile("s_waitcnt lgkmcnt(0)" ::: "memory");
            __builtin_amdgcn_sched_barrier(0);
        }
    }

    // ---- loss = -ln2 * (log2(alpha255 + alpha256) + etot) ----
    {
        const float a255 = rlane(a3, 63);   // state 255 = lane 63, k=3
        const float s    = a255 + a256;
        const float loss = -kLn2 * (LOG2(s) + etot);
        if (lane == 0) out[b] = loss;
    }
}

} // namespace

extern "C" void kernel_launch(void* const* d_in, const int* in_sizes, int n_in,
                              void* d_out, int out_size, void* d_ws, size_t ws_size,
                              hipStream_t stream) {
    const int*   labels = (const int*)d_in[0];   // y_true [256,128] int32
    const float* y_pred = (const float*)d_in[1]; // y_pred [256,512,512] f32
    float*       out    = (float*)d_out;         // loss [256,1] f32
    (void)in_sizes; (void)n_in; (void)d_ws; (void)ws_size;
    hipLaunchKernelGGL(ctc_fwd_kernel, dim3(out_size), dim3(64), 0, stream,
                       labels, y_pred, out);
}

// Round 16
// 51.561 us; speedup vs baseline: 1.1606x; 1.1606x over previous
//
#include <hip/hip_runtime.h>

namespace {

constexpr int   kT = 512, kC = 512, kL = 128, kBlank = 511;
constexpr int   kCH  = 16;         // rows per chunk
constexpr int   kNCH = kT / kCH;   // 32 chunks
constexpr float kEps = 1e-7f, kLn2 = 0.6931471805599453f;

typedef float __attribute__((address_space(1))) f32g;
typedef float __attribute__((address_space(3))) f32l;

__device__ __forceinline__ void glds16(const float* g, float* l) {
    __builtin_amdgcn_global_load_lds((const f32g*)g, (f32l*)l, 16, 0, 0);
}
__device__ __forceinline__ float rlane(float x, int l) {
    return __int_as_float(__builtin_amdgcn_readlane(__float_as_int(x), l));
}
__device__ __forceinline__ float bperm(int a, float x) {
    return __int_as_float(__builtin_amdgcn_ds_bpermute(a, __float_as_int(x)));
}
__device__ __forceinline__ float LOG2(float x) { return __builtin_amdgcn_logf(x); }

__device__ __forceinline__ void barrier_raw() {
    asm volatile("" ::: "memory");
    __builtin_amdgcn_s_barrier();
    asm volatile("" ::: "memory");
}

__global__ __launch_bounds__(128, 1) void ctc_fwd_kernel(
        const int* __restrict__ labels,
        const float* __restrict__ y_pred,
        float* __restrict__ out) {
    __shared__ __align__(16) float buf[3][kCH][kC];   // 96 KiB chunk ring

    const int tid  = (int)threadIdx.x;
    const int lane = tid & 63;
    const int wv   = tid >> 6;           // 0 = consumer, 1 = producer
    const int b    = (int)blockIdx.x;
    const float* yp  = y_pred + (size_t)b * kT * kC;
    const int*   lab = labels + b * kL;

    // consumer constants: state s = 4*lane + k (k=0..3), + scalar 256
    int   cls1 = kBlank, cls3 = kBlank;
    float skp1 = 0.f, skp3 = 0.f;
    if (wv == 0) {
        cls1 = lab[2 * lane];
        cls3 = lab[2 * lane + 1];
        skp1 = (lane >= 1 && lab[2 * lane] != lab[2 * lane - 1]) ? 1.f : 0.f;
        skp3 = (lab[2 * lane + 1] != lab[2 * lane]) ? 1.f : 0.f;
    }
    const int addr1 = (lane - 1) << 2;

    // ping-pong per-chunk register caches
    float gA_rb[kCH], gA_r1[kCH], gA_r3[kCH];
    float gB_rb[kCH], gB_r1[kCH], gB_r3[kCH];

    // rotating ring pointers: bC = slot of chunk c, bN = c+1, bP = c+2
    float (*bC)[kC] = buf[0];
    float (*bN)[kC] = buf[1];
    float (*bP)[kC] = buf[2];

    // ---- prologue: producer issues chunks 0,1,2; waits -> 0,1 resident ----
    if (wv == 1) {
        for (int ch = 0; ch < 3; ++ch)
            for (int r = 0; r < kCH; ++r) {
                const float* row = yp + (size_t)(ch * kCH + r) * kC;
                glds16(row + lane * 4,       &buf[ch][r][0]);
                glds16(row + 256 + lane * 4, &buf[ch][r][256]);
            }
        asm volatile("s_waitcnt vmcnt(32)" ::: "memory");
    }
    barrier_raw();
    if (wv == 0) {   // pre-gather chunk 0 into gA
#pragma unroll
        for (int r = 0; r < kCH; ++r) {
            gA_rb[r] = bC[r][kBlank];
            gA_r1[r] = bC[r][cls1];
            gA_r3[r] = bC[r][cls3];
        }
        asm volatile("s_waitcnt lgkmcnt(0)" ::: "memory");
    }
    barrier_raw();   // chunk-0 slot now safe to overwrite (iter 0 producer)

    float a0 = 0.f, a1 = 0.f, a2 = 0.f, a3 = 0.f, a256 = 0.f, etot = 0.f;
    float inj = (lane == 0) ? 1.f : 0.f;

    // One chunk: producer = r13 verbatim; consumer = steps on CUR with
    // chunk-(c+1) gathers into NXT interleaved (independent of the chain).
#define CHUNK_BODY(C_, CUR, NXT, GATHER_)                                     \
    {                                                                         \
        if (wv == 1) {                                                        \
            if ((C_) + 3 < kNCH) {                                            \
                for (int r = 0; r < kCH; ++r) {                               \
                    const float* row = yp + (size_t)(((C_) + 3) * kCH + r) * kC; \
                    glds16(row + lane * 4,       &bC[r][0]);                  \
                    glds16(row + 256 + lane * 4, &bC[r][256]);                \
                }                                                             \
                asm volatile("s_waitcnt vmcnt(32)" ::: "memory");             \
            } else if ((C_) == kNCH - 3) {                                    \
                asm volatile("s_waitcnt vmcnt(0)" ::: "memory");              \
            }                                                                 \
        } else {                                                              \
            _Pragma("unroll")                                                 \
            for (int r = 0; r < kCH; ++r) {                                   \
                float sh3 = bperm(addr1, a3);                                 \
                sh3 = (lane == 0) ? 0.f : sh3;                                \
                if (GATHER_) {                                                \
                    NXT##_rb[r] = bN[r][kBlank];                              \
                    NXT##_r1[r] = bN[r][cls1];                                \
                    NXT##_r3[r] = bN[r][cls3];                                \
                }                                                             \
                const float pb = CUR##_rb[r] + kEps;                          \
                const float p1 = CUR##_r1[r] + kEps;                          \
                const float p3 = CUR##_r3[r] + kEps;                          \
                const float a255 = rlane(a3, 63);                             \
                const float b0 = (a0 + sh3 + inj) * pb;                       \
                const float b1 = (a1 + a0 + skp1 * sh3 + inj) * p1;           \
                const float b2 = (a2 + a1) * pb;                              \
                const float b3 = (a3 + a2 + skp3 * a1) * p3;                  \
                a256 = (a256 + a255) * pb;                                    \
                a0 = b0; a1 = b1; a2 = b2; a3 = b3;                           \
                inj = 0.f;                                                    \
            }                                                                 \
            asm volatile("s_waitcnt lgkmcnt(0)" ::: "memory");                \
            if ((C_) & 1) {                                                   \
                float m = fmaxf(fmaxf(a0, a1), fmaxf(a2, a3));                \
                _Pragma("unroll")                                             \
                for (int i = 1; i < 64; i <<= 1) m = fmaxf(m, __shfl_xor(m, i)); \
                m = fmaxf(m, a256);                                           \
                const int ex = (__float_as_int(m) >> 23) & 0xFF;              \
                if (ex > 1) {                                                 \
                    const float sc = __int_as_float((254 - ex) << 23);        \
                    a0 *= sc; a1 *= sc; a2 *= sc; a3 *= sc; a256 *= sc;       \
                    etot += (float)(ex - 127);                                \
                }                                                             \
            }                                                                 \
        }                                                                     \
        barrier_raw();                                                        \
        float (*tmp_)[kC] = bC; bC = bN; bN = bP; bP = tmp_;                  \
    }

    // main loop: chunk pairs c = 0..29 (gathers always valid: c+1 <= 30)
    for (int cp = 0; cp < 15; ++cp) {
        const int c = 2 * cp;
        CHUNK_BODY(c,     gA, gB, true);
        CHUNK_BODY(c + 1, gB, gA, true);
    }
    // peeled tail: c = 30 (gathers chunk 31), c = 31 (no gathers)
    CHUNK_BODY(30, gA, gB, true);
    CHUNK_BODY(31, gB, gA, false);
#undef CHUNK_BODY

    // ---- loss = -ln2 * (log2(alpha255 + alpha256) + etot) ----
    if (wv == 0) {
        const float a255 = rlane(a3, 63);
        const float s    = a255 + a256;
        const float loss = -kLn2 * (LOG2(s) + etot);
        if (lane == 0) out[b] = loss;
    }
}

} // namespace

extern "C" void kernel_launch(void* const* d_in, const int* in_sizes, int n_in,
                              void* d_out, int out_size, void* d_ws, size_t ws_size,
                              hipStream_t stream) {
    const int*   labels = (const int*)d_in[0];   // y_true [256,128] int32
    const float* y_pred = (const float*)d_in[1]; // y_pred [256,512,512] f32
    float*       out    = (float*)d_out;         // loss [256,1] f32
    (void)in_sizes; (void)n_in; (void)d_ws; (void)ws_size;
    hipLaunchKernelGGL(ctc_fwd_kernel, dim3(out_size), dim3(128), 0, stream,
                       labels, y_pred, out);
}

// Round 17
// 45.768 us; speedup vs baseline: 1.3075x; 1.1266x over previous
//
#include <hip/hip_runtime.h>

namespace {

constexpr int   kT = 512, kC = 512, kL = 128, kBlank = 511;
constexpr int   kCH  = 16;         // rows per chunk
constexpr int   kNCH = kT / kCH;   // 32 chunks
constexpr float kEps = 1e-7f, kLn2 = 0.6931471805599453f;

typedef float __attribute__((address_space(1))) f32g;
typedef float __attribute__((address_space(3))) f32l;

__device__ __forceinline__ void glds16(const float* g, float* l) {
    __builtin_amdgcn_global_load_lds((const f32g*)g, (f32l*)l, 16, 0, 0);
}
__device__ __forceinline__ float rlane(float x, int l) {
    return __int_as_float(__builtin_amdgcn_readlane(__float_as_int(x), l));
}
// VALU-pipe lane shift: lane i <- lane i-1, lane 0 <- old (=0).
// Replaces the DS-pipe ds_bpermute (~100 cy) with ~4-8 cy dependent latency.
__device__ __forceinline__ float dpp_shr1(float x) {
    return __int_as_float(__builtin_amdgcn_update_dpp(
        0, __float_as_int(x), 0x138 /*WAVE_SHR1*/, 0xF, 0xF, false));
}
__device__ __forceinline__ float LOG2(float x) { return __builtin_amdgcn_logf(x); }

__device__ __forceinline__ void barrier_raw() {
    asm volatile("" ::: "memory");
    __builtin_amdgcn_s_barrier();
    asm volatile("" ::: "memory");
}

__global__ __launch_bounds__(128, 1) void ctc_fwd_kernel(
        const int* __restrict__ labels,
        const float* __restrict__ y_pred,
        float* __restrict__ out) {
    __shared__ __align__(16) float buf[3][kCH][kC];   // 96 KiB chunk ring

    const int tid  = (int)threadIdx.x;
    const int lane = tid & 63;
    const int wv   = tid >> 6;           // 0 = consumer, 1 = producer
    const int b    = (int)blockIdx.x;
    const float* yp  = y_pred + (size_t)b * kT * kC;
    const int*   lab = labels + b * kL;

    // consumer constants: state s = 4*lane + k (k=0..3), + scalar 256
    int   cls1 = kBlank, cls3 = kBlank;
    float skp1 = 0.f, skp3 = 0.f;
    if (wv == 0) {
        cls1 = lab[2 * lane];
        cls3 = lab[2 * lane + 1];
        skp1 = (lane >= 1 && lab[2 * lane] != lab[2 * lane - 1]) ? 1.f : 0.f;
        skp3 = (lab[2 * lane + 1] != lab[2 * lane]) ? 1.f : 0.f;
    }

    // ping-pong per-chunk register caches
    float gA_rb[kCH], gA_r1[kCH], gA_r3[kCH];
    float gB_rb[kCH], gB_r1[kCH], gB_r3[kCH];

    // rotating ring pointers: bC = slot of chunk c, bN = c+1, bP = c+2
    float (*bC)[kC] = buf[0];
    float (*bN)[kC] = buf[1];
    float (*bP)[kC] = buf[2];

    // ---- prologue: producer issues chunks 0,1,2; waits -> 0,1 resident ----
    if (wv == 1) {
        for (int ch = 0; ch < 3; ++ch)
            for (int r = 0; r < kCH; ++r) {
                const float* row = yp + (size_t)(ch * kCH + r) * kC;
                glds16(row + lane * 4,       &buf[ch][r][0]);
                glds16(row + 256 + lane * 4, &buf[ch][r][256]);
            }
        asm volatile("s_waitcnt vmcnt(32)" ::: "memory");
    }
    barrier_raw();
    if (wv == 0) {   // pre-gather chunk 0 into gA
#pragma unroll
        for (int r = 0; r < kCH; ++r) {
            gA_rb[r] = bC[r][kBlank];
            gA_r1[r] = bC[r][cls1];
            gA_r3[r] = bC[r][cls3];
        }
        asm volatile("s_waitcnt lgkmcnt(0)" ::: "memory");
    }
    barrier_raw();   // chunk-0 slot now safe to overwrite (iter 0 producer)

    float a0 = 0.f, a1 = 0.f, a2 = 0.f, a3 = 0.f, a256 = 0.f, etot = 0.f;
    float inj = (lane == 0) ? 1.f : 0.f;

    // One chunk: producer = r13 verbatim; consumer = steps on CUR with
    // chunk-(c+1) gathers into NXT interleaved (independent of the chain).
#define CHUNK_BODY(C_, CUR, NXT, GATHER_)                                     \
    {                                                                         \
        if (wv == 1) {                                                        \
            if ((C_) + 3 < kNCH) {                                            \
                for (int r = 0; r < kCH; ++r) {                               \
                    const float* row = yp + (size_t)(((C_) + 3) * kCH + r) * kC; \
                    glds16(row + lane * 4,       &bC[r][0]);                  \
                    glds16(row + 256 + lane * 4, &bC[r][256]);                \
                }                                                             \
                asm volatile("s_waitcnt vmcnt(32)" ::: "memory");             \
            } else if ((C_) == kNCH - 3) {                                    \
                asm volatile("s_waitcnt vmcnt(0)" ::: "memory");              \
            }                                                                 \
        } else {                                                              \
            _Pragma("unroll")                                                 \
            for (int r = 0; r < kCH; ++r) {                                   \
                float sh3 = dpp_shr1(a3);                                     \
                sh3 = (lane == 0) ? 0.f : sh3;                                \
                if (GATHER_) {                                                \
                    NXT##_rb[r] = bN[r][kBlank];                              \
                    NXT##_r1[r] = bN[r][cls1];                                \
                    NXT##_r3[r] = bN[r][cls3];                                \
                }                                                             \
                const float pb = CUR##_rb[r] + kEps;                          \
                const float p1 = CUR##_r1[r] + kEps;                          \
                const float p3 = CUR##_r3[r] + kEps;                          \
                const float a255 = rlane(a3, 63);                             \
                const float b0 = (a0 + sh3 + inj) * pb;                       \
                const float b1 = (a1 + a0 + skp1 * sh3 + inj) * p1;           \
                const float b2 = (a2 + a1) * pb;                              \
                const float b3 = (a3 + a2 + skp3 * a1) * p3;                  \
                a256 = (a256 + a255) * pb;                                    \
                a0 = b0; a1 = b1; a2 = b2; a3 = b3;                           \
                inj = 0.f;                                                    \
            }                                                                 \
            asm volatile("s_waitcnt lgkmcnt(0)" ::: "memory");                \
            if ((C_) & 1) {                                                   \
                float m = fmaxf(fmaxf(a0, a1), fmaxf(a2, a3));                \
                _Pragma("unroll")                                             \
                for (int i = 1; i < 64; i <<= 1) m = fmaxf(m, __shfl_xor(m, i)); \
                m = fmaxf(m, a256);                                           \
                const int ex = (__float_as_int(m) >> 23) & 0xFF;              \
                if (ex > 1) {                                                 \
                    const float sc = __int_as_float((254 - ex) << 23);        \
                    a0 *= sc; a1 *= sc; a2 *= sc; a3 *= sc; a256 *= sc;       \
                    etot += (float)(ex - 127);                                \
                }                                                             \
            }                                                                 \
        }                                                                     \
        barrier_raw();                                                        \
        float (*tmp_)[kC] = bC; bC = bN; bN = bP; bP = tmp_;                  \
    }

    // main loop: chunk pairs c = 0..29 (gathers always valid: c+1 <= 30)
    for (int cp = 0; cp < 15; ++cp) {
        const int c = 2 * cp;
        CHUNK_BODY(c,     gA, gB, true);
        CHUNK_BODY(c + 1, gB, gA, true);
    }
    // peeled tail: c = 30 (gathers chunk 31), c = 31 (no gathers)
    CHUNK_BODY(30, gA, gB, true);
    CHUNK_BODY(31, gB, gA, false);
#undef CHUNK_BODY

    // ---- loss = -ln2 * (log2(alpha255 + alpha256) + etot) ----
    if (wv == 0) {
        const float a255 = rlane(a3, 63);
        const float s    = a255 + a256;
        const float loss = -kLn2 * (LOG2(s) + etot);
        if (lane == 0) out[b] = loss;
    }
}

} // namespace

extern "C" void kernel_launch(void* const* d_in, const int* in_sizes, int n_in,
                              void* d_out, int out_size, void* d_ws, size_t ws_size,
                              hipStream_t stream) {
    const int*   labels = (const int*)d_in[0];   // y_true [256,128] int32
    const float* y_pred = (const float*)d_in[1]; // y_pred [256,512,512] f32
    float*       out    = (float*)d_out;         // loss [256,1] f32
    (void)in_sizes; (void)n_in; (void)d_ws; (void)ws_size;
    hipLaunchKernelGGL(ctc_fwd_kernel, dim3(out_size), dim3(128), 0, stream,
                       labels, y_pred, out);
}